// Round 1
// baseline (501.815 us; speedup 1.0000x reference)
//
#include <hip/hip_runtime.h>
#include <hip/hip_bf16.h>

// LSTM: B=512, T=4096, I=1, H=16, O=1. f32 in/out.
// One wave (64 lanes) per batch element. Lane l: gate k=l&3 (i,f,g,o order),
// hidden unit j=l>>2, i.e. W_hh/W_ih row r = 16*k + j.
// h broadcast across the wave via v_readlane -> SGPRs (16 scalars).
// i/f/g/o regrouping is intra-quad -> DPP quad_perm broadcasts.
// FC (O=1) partials accumulated in an LDS tile, flushed every 64 steps.

constexpr int NB = 512;   // batch
constexpr int NT = 4096;  // timesteps

template<int CTRL>
__device__ __forceinline__ float qbcast(float x) {
  // quad_perm broadcast within each group of 4 lanes
  return __int_as_float(__builtin_amdgcn_mov_dpp(__float_as_int(x), CTRL, 0xF, 0xF, true));
}

__device__ __forceinline__ float rdlane(float x, int lane) {
  return __int_as_float(__builtin_amdgcn_readlane(__float_as_int(x), lane));
}

#if __has_builtin(__builtin_amdgcn_exp2f)
  #define EXP2(x) __builtin_amdgcn_exp2f(x)
#else
  #define EXP2(x) exp2f(x)
#endif
#if __has_builtin(__builtin_amdgcn_rcpf)
  #define RCPF(x) __builtin_amdgcn_rcpf(x)
#else
  #define RCPF(x) (1.0f / (x))
#endif

__global__ __launch_bounds__(64, 1) void lstm_fused(
    const float* __restrict__ x,     // [B, T]
    const float* __restrict__ W_ih,  // [64, 1]
    const float* __restrict__ W_hh,  // [64, 16]
    const float* __restrict__ b_ih,  // [64]
    const float* __restrict__ b_hh,  // [64]
    const float* __restrict__ W_fc,  // [1, 16]
    const float* __restrict__ b_fc,  // [1]
    float* __restrict__ out)         // [B, T]
{
  __shared__ float tile[64 * 65];    // [t%64][lane], stride 65 -> conflict-free
  const int b = blockIdx.x;
  const int l = threadIdx.x;         // 0..63
  const int j = l >> 2;              // hidden unit
  const int k = l & 3;               // 0=i 1=f 2=g 3=o (PyTorch gate order)
  const int r = k * 16 + j;          // gate row in [4H]

  constexpr float LOG2E = 1.4426950408889634f;
  // Fold the exp2 scale into the weights: sigmoid(v)=1/(1+exp2(-v*log2e)),
  // tanh(v)=2/(1+exp2(-2v*log2e))-1 -> scale = -log2e (x2 for g-gate).
  const float sc = (k == 2) ? (-2.0f * LOG2E) : (-LOG2E);

  float wrow[16];
  #pragma unroll
  for (int q = 0; q < 16; ++q) wrow[q] = W_hh[r * 16 + q] * sc;
  const float wx    = W_ih[r] * sc;
  const float wb    = (b_ih[r] + b_hh[r]) * sc;
  const float act_m = (k == 2) ? 2.0f : 1.0f;   // act = r1*m + a
  const float act_a = (k == 2) ? -1.0f : 0.0f;
  const float wfc   = W_fc[j] * 0.25f;          // each h_j replicated x4 in wave
  const float bfc   = b_fc[0];

  const float* xb = x + (size_t)b * NT;
  float*       ob = out + (size_t)b * NT;

  float c = 0.0f;
  float sh[16];                      // wave-uniform h (SGPRs via readlane)
  #pragma unroll
  for (int q = 0; q < 16; ++q) sh[q] = 0.0f;

  float xcur = xb[l];                // lane l holds x[t0 + l] for this 64-chunk

  for (int blk = 0; blk < NT / 64; ++blk) {
    float xnext = 0.0f;
    if (blk + 1 < NT / 64) xnext = xb[(blk + 1) * 64 + l];  // prefetch

    #pragma unroll 8
    for (int tt = 0; tt < 64; ++tt) {
      const float sx = rdlane(xcur, tt);       // wave-uniform x_t
      // gates_r = sc*( x*W_ih[r] + b_ih[r]+b_hh[r] + sum_j W_hh[r][j]*h_j )
      float a0 = fmaf(wx, sx, wb);
      a0 = fmaf(wrow[0], sh[0], a0);
      float a1 = wrow[1] * sh[1];
      float a2 = wrow[2] * sh[2];
      float a3 = wrow[3] * sh[3];
      #pragma unroll
      for (int q = 4; q < 16; q += 4) {
        a0 = fmaf(wrow[q + 0], sh[q + 0], a0);
        a1 = fmaf(wrow[q + 1], sh[q + 1], a1);
        a2 = fmaf(wrow[q + 2], sh[q + 2], a2);
        a3 = fmaf(wrow[q + 3], sh[q + 3], a3);
      }
      const float z  = (a0 + a1) + (a2 + a3);
      const float e1 = EXP2(z);
      const float r1 = RCPF(1.0f + e1);        // sigmoid (or sig(2v) for g)
      const float act = fmaf(r1, act_m, act_a);// i/f/o: r1 ; g: 2*r1-1 = tanh
      const float ii = qbcast<0x00>(act);
      const float ff = qbcast<0x55>(act);
      const float gg = qbcast<0xAA>(act);
      const float oo = qbcast<0xFF>(act);
      c = fmaf(ff, c, ii * gg);
      const float e2 = EXP2(c * (-2.0f * LOG2E));
      const float r2 = RCPF(1.0f + e2);
      const float th = fmaf(2.0f, r2, -1.0f);  // tanh(c)
      const float h  = oo * th;
      tile[tt * 65 + l] = h * wfc;             // FC partial
      #pragma unroll
      for (int q = 0; q < 16; ++q) sh[q] = rdlane(h, 4 * q);
    }

    // Flush 64 outputs: out(t0+l) = b_fc + sum over 64 lane-partials of row l
    float s0 = bfc, s1 = 0.0f, s2 = 0.0f, s3 = 0.0f;
    #pragma unroll
    for (int i2 = 0; i2 < 64; i2 += 4) {
      s0 += tile[l * 65 + i2 + 0];
      s1 += tile[l * 65 + i2 + 1];
      s2 += tile[l * 65 + i2 + 2];
      s3 += tile[l * 65 + i2 + 3];
    }
    ob[blk * 64 + l] = (s0 + s1) + (s2 + s3);
    xcur = xnext;
  }
}

extern "C" void kernel_launch(void* const* d_in, const int* in_sizes, int n_in,
                              void* d_out, int out_size, void* d_ws, size_t ws_size,
                              hipStream_t stream) {
  const float* x    = (const float*)d_in[0];
  const float* W_ih = (const float*)d_in[1];
  const float* W_hh = (const float*)d_in[2];
  const float* b_ih = (const float*)d_in[3];
  const float* b_hh = (const float*)d_in[4];
  const float* W_fc = (const float*)d_in[5];
  const float* b_fc = (const float*)d_in[6];
  float* out = (float*)d_out;
  (void)in_sizes; (void)n_in; (void)out_size; (void)d_ws; (void)ws_size;
  lstm_fused<<<NB, 64, 0, stream>>>(x, W_ih, W_hh, b_ih, b_hh, W_fc, b_fc, out);
}

// Round 2
// 464.064 us; speedup vs baseline: 1.0813x; 1.0813x over previous
//
#include <hip/hip_runtime.h>
#include <hip/hip_bf16.h>

// LSTM: B=512, T=4096, I=1, H=16, O=1. f32 in/out.
// One wave per batch element. Lane l: gate k=l&3 (i,f,g,o), unit j=l>>2,
// row r=16k+j. h broadcast via v_readlane -> SGPRs. Quad-perm gate gather.
// R1: guaranteed single-instr v_exp/v_rcp via inline asm; cell state carried
// pre-scaled (cs = -2*log2e*c) so tanh(c) = 2*rcp(1+exp2(cs))-1 with no mul
// on the chain; h = fma(2*o, r2, -o) folds the *2-1 and the o-mul.

constexpr int NB = 512;   // batch
constexpr int NT = 4096;  // timesteps

template<int CTRL>
__device__ __forceinline__ float qbcast(float x) {
  return __int_as_float(__builtin_amdgcn_mov_dpp(__float_as_int(x), CTRL, 0xF, 0xF, true));
}
__device__ __forceinline__ float rdlane(float x, int lane) {
  return __int_as_float(__builtin_amdgcn_readlane(__float_as_int(x), lane));
}
__device__ __forceinline__ float vexp2(float x) {   // D = 2^x, single v_exp_f32
  float r; asm("v_exp_f32 %0, %1" : "=v"(r) : "v"(x)); return r;
}
__device__ __forceinline__ float vrcp(float x) {    // D = 1/x, single v_rcp_f32
  float r; asm("v_rcp_f32 %0, %1" : "=v"(r) : "v"(x)); return r;
}

__global__ __launch_bounds__(64, 1) void lstm_fused(
    const float* __restrict__ x,     // [B, T]
    const float* __restrict__ W_ih,  // [64, 1]
    const float* __restrict__ W_hh,  // [64, 16]
    const float* __restrict__ b_ih,  // [64]
    const float* __restrict__ b_hh,  // [64]
    const float* __restrict__ W_fc,  // [1, 16]
    const float* __restrict__ b_fc,  // [1]
    float* __restrict__ out)         // [B, T]
{
  __shared__ float tile[64 * 65];    // [t%64][lane], stride 65: conflict-free
  const int b = blockIdx.x;
  const int l = threadIdx.x;
  const int j = l >> 2;
  const int k = l & 3;               // 0=i 1=f 2=g 3=o
  const int r = k * 16 + j;

  constexpr float LOG2E = 1.4426950408889634f;
  constexpr float K2    = -2.0f * LOG2E;       // cs = K2 * c
  const float sc = (k == 2) ? K2 : -LOG2E;

  float wrow[16];
  #pragma unroll
  for (int q = 0; q < 16; ++q) wrow[q] = W_hh[r * 16 + q] * sc;
  const float wx    = W_ih[r] * sc;
  const float wb    = (b_ih[r] + b_hh[r]) * sc;
  // i/f/o lanes: act = sigmoid = r1. g lane: act = K2*tanh(zg) = r1*(2K2)-K2.
  const float act_m = (k == 2) ? (2.0f * K2) : 1.0f;
  const float act_a = (k == 2) ? (-K2)       : 0.0f;
  const float wfc   = W_fc[j] * 0.25f;         // h_j replicated x4 across wave
  const float bfc   = b_fc[0];

  const float* xb = x + (size_t)b * NT;
  float*       ob = out + (size_t)b * NT;

  float cs = 0.0f;                   // K2-scaled cell state
  float sh[16];
  #pragma unroll
  for (int q = 0; q < 16; ++q) sh[q] = 0.0f;

  float xcur = xb[l];

  for (int blk = 0; blk < NT / 64; ++blk) {
    float xnext = 0.0f;
    if (blk + 1 < NT / 64) xnext = xb[(blk + 1) * 64 + l];

    #pragma unroll 16
    for (int tt = 0; tt < 64; ++tt) {
      const float sx    = rdlane(xcur, tt);        // uniform x_t (off-chain)
      const float xinit = fmaf(wx, sx, wb);        // x-part + bias (off-chain)
      // z = xinit + sum_q wrow[q]*sh[q]; 4 accumulators, stride 4
      float a0 = fmaf(wrow[0], sh[0], xinit);
      float a1 = wrow[1] * sh[1];
      float a2 = wrow[2] * sh[2];
      float a3 = wrow[3] * sh[3];
      #pragma unroll
      for (int q = 4; q < 16; q += 4) {
        a0 = fmaf(wrow[q + 0], sh[q + 0], a0);
        a1 = fmaf(wrow[q + 1], sh[q + 1], a1);
        a2 = fmaf(wrow[q + 2], sh[q + 2], a2);
        a3 = fmaf(wrow[q + 3], sh[q + 3], a3);
      }
      const float z   = (a0 + a1) + (a2 + a3);
      const float e1  = vexp2(z);
      const float r1  = vrcp(1.0f + e1);
      const float act = fmaf(r1, act_m, act_a);    // i/f/o: sigma; g: K2*tanh
      const float ii  = qbcast<0x00>(act);
      const float ff  = qbcast<0x55>(act);
      const float ggs = qbcast<0xAA>(act);         // K2*tanh(zg)
      const float oo  = qbcast<0xFF>(act);
      const float oo2 = oo + oo;                   // off-chain
      cs = fmaf(ff, cs, ii * ggs);                 // K2-scaled cell update
      const float e2 = vexp2(cs);                  // = exp(-2c)
      const float r2 = vrcp(1.0f + e2);            // = sigma(2c)
      const float h  = fmaf(oo2, r2, -oo);         // = o * tanh(c)
      tile[tt * 65 + l] = h * wfc;                 // FC partial (off-chain)
      #pragma unroll
      for (int q = 0; q < 16; ++q) sh[q] = rdlane(h, 4 * q);
    }

    float s0 = bfc, s1 = 0.0f, s2 = 0.0f, s3 = 0.0f;
    #pragma unroll
    for (int i2 = 0; i2 < 64; i2 += 4) {
      s0 += tile[l * 65 + i2 + 0];
      s1 += tile[l * 65 + i2 + 1];
      s2 += tile[l * 65 + i2 + 2];
      s3 += tile[l * 65 + i2 + 3];
    }
    ob[blk * 64 + l] = (s0 + s1) + (s2 + s3);
    xcur = xnext;
  }
}

extern "C" void kernel_launch(void* const* d_in, const int* in_sizes, int n_in,
                              void* d_out, int out_size, void* d_ws, size_t ws_size,
                              hipStream_t stream) {
  const float* x    = (const float*)d_in[0];
  const float* W_ih = (const float*)d_in[1];
  const float* W_hh = (const float*)d_in[2];
  const float* b_ih = (const float*)d_in[3];
  const float* b_hh = (const float*)d_in[4];
  const float* W_fc = (const float*)d_in[5];
  const float* b_fc = (const float*)d_in[6];
  float* out = (float*)d_out;
  (void)in_sizes; (void)n_in; (void)out_size; (void)d_ws; (void)ws_size;
  lstm_fused<<<NB, 64, 0, stream>>>(x, W_ih, W_hh, b_ih, b_hh, W_fc, b_fc, out);
}